// Round 15
// baseline (30.427 us; speedup 1.0000x reference)
//
#include <hip/hip_runtime.h>
#include <math.h>

#define H_IN  1024
#define W_IN  1024
#define HW_IN (H_IN * W_IN)
#define H_OUT 768
#define W_OUT 768
#define HW_OUT (H_OUT * W_OUT)
#define SCALE_X (1024.f / 768.f)
#define SCALE_Y (1024.f / 768.f)

// LDS tile: 28 rows x 32 px, interleaved [p,s] per channel (R11 layout)
#define SROWS 28
#define SPX   32
#define RS    (SPX * 6 + 8)        // 200 floats/row
#define NLD4  (3 * SROWS * (SPX / 4))   // 672 float4 staging loads

typedef float v2f __attribute__((ext_vector_type(2)));

struct KC {
    float tsig1, msig1, atanh_scale;           // inv_sigmoid
    float slope, one_m_slope, half_over_sig1;  // ext_sigmoid
    float exp_a, exp_b;
    float a2, a0, m_in_root;                   // robidoux
};

__device__ __forceinline__ float fast_rcp(float x)  { return __builtin_amdgcn_rcpf(x); }
__device__ __forceinline__ float fast_log2(float x) { return __builtin_amdgcn_logf(x); }
__device__ __forceinline__ float fast_exp2(float x) { return __builtin_amdgcn_exp2f(x); }
__device__ __forceinline__ float fast_rsq(float x)  { return __builtin_amdgcn_rsqf(x); }

// Branchless inv_sigmoid, valid for q in [0,1) (this input's range).
__device__ __forceinline__ float inv_sigmoid(float q, const KC k) {
    float ssq = fmaf(k.tsig1, q, k.msig1);
    float ratio = (1.f + ssq) * fast_rcp(1.f - ssq);
    return fmaf(fast_log2(ratio), k.atanh_scale, 0.5f);
}

// Branchless ext_sigmoid (q = mitchell sum CAN leave [0,1]; keep selects).
__device__ __forceinline__ float ext_sigmoid(float q, const KC k) {
    float lo = k.slope * q;
    float e  = fast_exp2(fmaf(k.exp_a, q, k.exp_b));
    float th = fmaf(-2.f, fast_rcp(e + 1.f), 1.f);
    float mid = fmaf(k.half_over_sig1, th, 0.5f);
    float v = (q <= 0.f) ? lo : mid;
    return (q >= 1.f) ? (lo + k.one_m_slope) : v;
}

// Branchless Mitchell (exact 0 for |x|>=2 -> natural tap masking)
__device__ __forceinline__ float mitchell_b(float xv) {
    float ax = fabsf(xv);
    float v1 = fmaf(ax * ax, fmaf(7.f / 6.f, ax, -2.f), 8.f / 9.f);
    float v2 = fmaf(fmaf(fmaf(-7.f / 18.f, ax, 2.f), ax, -10.f / 3.f), ax, 16.f / 9.f);
    float v = (ax < 1.f) ? v1 : v2;
    return (ax < 2.f) ? v : 0.f;
}

// Branchless Robidoux
__device__ __forceinline__ float robidoux_b(float r2, const KC k) {
    float r = sqrtf(r2 + 1e-8f);
    float w_in = fmaf(r2, fmaf(-3.f, r, k.a2), k.a0);
    float t = r - 2.f;
    float w_out = (r + k.m_in_root) * (t * t);
    float w = (r2 < 1.f) ? w_in : w_out;
    return (r2 < 4.f) ? w : 0.f;
}

__global__ __launch_bounds__(256, 3)
void lohalo_fused(const float* __restrict__ img, const float* __restrict__ grid,
                  float* __restrict__ out, KC k) {
    __shared__ float sm[SROWS * RS];   // 22400 B

    // XCD-aware swizzle: 2304 blocks, 288 contiguous per XCD
    const int bid = blockIdx.x;
    const int swz = (bid & 7) * 288 + (bid >> 3);
    const int bx = swz % 48, by = swz / 48;

    const int tid = threadIdx.x;
    const int lx = tid & 15, ly = tid >> 4;
    const int x = bx * 16 + lx;
    const int y = by * 16 + ly;
    const int pix = y * W_OUT + x;

    // ---- Jacobian (grid loads issue first, as in R11) ----
    const float2* G = (const float2*)grid;
    float2 gc  = G[pix];
    float2 gxm = G[y * W_OUT + max(x - 1, 0)];
    float2 gxp = G[y * W_OUT + min(x + 1, W_OUT - 1)];
    float2 gym = G[max(y - 1, 0) * W_OUT + x];
    float2 gyp = G[min(y + 1, H_OUT - 1) * W_OUT + x];
    float J00 = (gxp.x - gxm.x) * 0.5f, J10 = (gxp.y - gxm.y) * 0.5f;
    float J01 = (gyp.x - gym.x) * 0.5f, J11 = (gyp.y - gym.y) * 0.5f;
    float det = J00 * J11 - J01 * J10 + 1e-8f;
    float idet = fast_rcp(det);
    float a  = J11 * idet, b = -J01 * idet;
    float cI = -J10 * idet, d = J00 * idet;
    float n11 = a * a + b * b, n12 = a * cI + b * d, n22 = cI * cI + d * d;
    float frob = n11 + n22;
    float disc = frob * frob - 4.f * idet * idet;
    float sdisc = sqrtf(fmaxf(disc, 0.f));
    float twice = frob + sdisc;
    float s1s1 = 0.5f * twice, s2s2 = 0.5f * (frob - sdisc);
    float rmaj = fast_rsq(fmaxf(s1s1, 1.f));
    float rmin = fast_rsq(fmaxf(s2s2, 1.f));
    float diff1 = s1s1 - n11, diff2 = s1s1 - n22;
    bool  cnd  = diff1 * diff1 >= diff2 * diff2;
    float tu11 = cnd ? n12 : diff2;
    float tu21 = cnd ? diff1 : n12;
    float nrm = sqrtf(tu11 * tu11 + tu21 * tu21);
    float inrm = fast_rcp(nrm);
    float u11 = nrm > 0.f ? tu11 * inrm : 1.f;
    float u21 = nrm > 0.f ? tu21 * inrm : 0.f;
    float cMx = u11 * rmaj, cMy = u21 * rmaj;
    float cmx = -u21 * rmin, cmy = u11 * rmin;
    float theta = rmaj * rmin;
    bool need_ewa = twice > 2.f;

    float fix = floorf(gc.x), fiy = floorf(gc.y);
    int ix = (int)fix, iy = (int)fiy;
    float fx = gc.x - (fix + 0.5f);
    float fy = gc.y - (fiy + 0.5f);

    // ---- ANALYTIC tile origin (replaces bbox reduce + its barrier) ----
    const int x0 = (((int)floorf(fmaf(16.f * bx + 0.5f, SCALE_X, -0.25f)) - 2) & ~3);
    const int y0 = ((int)floorf(fmaf(16.f * by + 0.5f, SCALE_Y, -0.25f))) - 2;

    // per-thread window-fits check (correct for ANY grid)
    const bool fits = (ix - 2 - x0 >= 0) && (ix - x0 <= SPX - 4) &&
                      (iy - 2 - y0 >= 0) && (iy - y0 <= SROWS - 4);

    // ---- Mitchell x-weights (mx6[5] naturally exact 0) ----
    float mx6[6];
#pragma unroll
    for (int t = 0; t < 6; t++) mx6[t] = mitchell_b(fx - (float)(t - 2));
    const float fxp2 = fx + 2.f;

    // packed accumulators: .x = EWA(p), .y = Mitchell(s)
    v2f a0 = {0.f, 0.f}, a1 = {0.f, 0.f}, a2acc = {0.f, 0.f};
    float tw = 0.f;

    // ---- staging (unconditional; R11 layout & loop) ----
    if (x0 >= 0 && x0 + SPX <= W_IN) {
        for (int j = tid; j < NLD4; j += 256) {
            int p   = j / (SROWS * (SPX / 4));
            int rem = j - p * (SROWS * (SPX / 4));
            int r   = rem >> 3;
            int q   = rem & 7;
            int gr  = min(max(y0 + r, 0), H_IN - 1);
            float4 v = *(const float4*)&img[(size_t)p * HW_IN + (size_t)gr * W_IN + x0 + q * 4];
            float* o = &sm[r * RS + (q * 4) * 6 + p * 2];
            *(float2*)(o)      = make_float2(v.x, inv_sigmoid(v.x, k));
            *(float2*)(o + 6)  = make_float2(v.y, inv_sigmoid(v.y, k));
            *(float2*)(o + 12) = make_float2(v.z, inv_sigmoid(v.z, k));
            *(float2*)(o + 18) = make_float2(v.w, inv_sigmoid(v.w, k));
        }
    } else {
        for (int j = tid; j < SROWS * SPX; j += 256) {
            int r = j / SPX;
            int c = j - r * SPX;
            int gr  = min(max(y0 + r, 0), H_IN - 1);
            int gcc = min(max(x0 + c, 0), W_IN - 1);
            const float* base = &img[(size_t)gr * W_IN + gcc];
            int o = r * RS + c * 6;
#pragma unroll
            for (int p = 0; p < 3; p++) {
                float pv = base[(size_t)p * HW_IN];
                *(float2*)&sm[o + p * 2] = make_float2(pv, inv_sigmoid(pv, k));
            }
        }
    }
    __syncthreads();

    if (fits) {
        const float* sp = &sm[(iy - 2 - y0) * RS + (ix - 2 - x0) * 6];
        const v2f cM = {cMx, cmx};
#pragma unroll
        for (int ty = 0; ty < 6; ty++) {
            float rely = fy - (float)(ty - 2);
            float wmy = mitchell_b(rely);          // exact 0 for ty=5 band
            v2f q = { fmaf(fxp2, cMx, rely * cMy),
                      fmaf(fxp2, cmx, rely * cmy) };
            float mxw[6];
#pragma unroll
            for (int t = 0; t < 6; t++) mxw[t] = mx6[t] * wmy;
            const float* rp = sp + ty * RS;
#pragma unroll
            for (int tx = 0; tx < 6; tx++) {
                v2f f0 = *(const v2f*)(rp + tx * 6);
                v2f f1 = *(const v2f*)(rp + tx * 6 + 2);
                v2f f2 = *(const v2f*)(rp + tx * 6 + 4);
                float r2 = fmaf(q.x, q.x, q.y * q.y);
                float we = robidoux_b(r2, k);
                tw += we;
                v2f w = { we, mxw[tx] };
                a0    = __builtin_elementwise_fma(f0, w, a0);
                a1    = __builtin_elementwise_fma(f1, w, a1);
                a2acc = __builtin_elementwise_fma(f2, w, a2acc);
                q = q - cM;
            }
        }
    } else {
        // rare (border/anomalous grid): direct gather with per-tap clamp + sigmoid
#pragma unroll
        for (int ty = 0; ty < 6; ty++) {
            float rely = fy - (float)(ty - 2);
            float wmy = mitchell_b(rely);
            float q1 = fmaf(fxp2, cMx, rely * cMy);
            float q2 = fmaf(fxp2, cmx, rely * cmy);
            const int gy2 = min(max(iy + (ty - 2), 0), H_IN - 1);
            const int rb = gy2 * W_IN;
#pragma unroll
            for (int tx = 0; tx < 6; tx++) {
                const int off = rb + min(max(ix + (tx - 2), 0), W_IN - 1);
                float p0 = img[off];
                float p1 = img[off + HW_IN];
                float p2 = img[off + 2 * HW_IN];
                float mxw = mx6[tx] * wmy;
                float r2 = fmaf(q1, q1, q2 * q2);
                float we = robidoux_b(r2, k);
                tw += we;
                a0.x    = fmaf(p0, we, a0.x);
                a1.x    = fmaf(p1, we, a1.x);
                a2acc.x = fmaf(p2, we, a2acc.x);
                a0.y    = fmaf(inv_sigmoid(p0, k), mxw, a0.y);
                a1.y    = fmaf(inv_sigmoid(p1, k), mxw, a1.y);
                a2acc.y = fmaf(inv_sigmoid(p2, k), mxw, a2acc.y);
                q1 -= cMx;
                q2 -= cmx;
            }
        }
    }

    tw += 1e-8f;
    float itw = fast_rcp(tw);
    float mv0 = ext_sigmoid(a0.y, k);
    float mv1 = ext_sigmoid(a1.y, k);
    float mv2 = ext_sigmoid(a2acc.y, k);
    float om = 1.f - theta;
    out[pix]              = need_ewa ? theta * mv0 + om * (a0.x * itw)    : mv0;
    out[HW_OUT + pix]     = need_ewa ? theta * mv1 + om * (a1.x * itw)    : mv1;
    out[2 * HW_OUT + pix] = need_ewa ? theta * mv2 + om * (a2acc.x * itw) : mv2;
}

extern "C" void kernel_launch(void* const* d_in, const int* in_sizes, int n_in,
                              void* d_out, int out_size, void* d_ws, size_t ws_size,
                              hipStream_t stream) {
    const float* img  = (const float*)d_in[0];
    const float* grid = (const float*)d_in[1];
    float* out = (float*)d_out;

    KC k;
    const double cc = 3.38589;
    const double s1 = tanh(0.25 * cc);
    const double slope = (1.0 / s1 - s1) * 0.25 * cc;
    const double log2e = 1.4426950408889634074;
    const double ln2   = 0.6931471805599453094;
    k.tsig1 = (float)(2.0 * s1);
    k.msig1 = (float)(-s1);
    k.atanh_scale = (float)(ln2 / cc);
    k.slope = (float)slope;
    k.one_m_slope = (float)(1.0 - slope);
    k.half_over_sig1 = (float)(0.5 / s1);
    k.exp_a = (float)(cc * log2e);
    k.exp_b = (float)(-0.5 * cc * log2e);
    const double sq2 = sqrt(2.0);
    k.a2 = (float)((45739.0 + 7164.0 * sq2) / 10319.0);
    k.a0 = (float)((-8926.0 - 14328.0 * sq2) / 10319.0);
    k.m_in_root = (float)((-103.0 - 36.0 * sq2) / (7.0 + 72.0 * sq2));

    lohalo_fused<<<(W_OUT / 16) * (H_OUT / 16), 256, 0, stream>>>(img, grid, out, k);
}

// Round 16
// 26.731 us; speedup vs baseline: 1.1383x; 1.1383x over previous
//
#include <hip/hip_runtime.h>
#include <math.h>

#define H_IN  1024
#define W_IN  1024
#define HW_IN (H_IN * W_IN)
#define H_OUT 768
#define W_OUT 768
#define HW_OUT (H_OUT * W_OUT)

// LDS tile: 28 rows x 32 px, interleaved [p,s] per channel, clamped at stage time
#define SROWS 28
#define SPX   32
#define RS    (SPX * 6 + 8)        // 200 floats/row; %32 = 8 bank stagger
#define NLD4  (3 * SROWS * (SPX / 4))   // 672 float4 staging loads

typedef float v2f __attribute__((ext_vector_type(2)));

struct KC {
    float tsig1, msig1, atanh_scale;           // inv_sigmoid
    float slope, one_m_slope, half_over_sig1;  // ext_sigmoid
    float exp_a, exp_b;
    float a2, a0, m_in_root;                   // robidoux
};

__device__ __forceinline__ float fast_rcp(float x)  { return __builtin_amdgcn_rcpf(x); }
__device__ __forceinline__ float fast_log2(float x) { return __builtin_amdgcn_logf(x); }   // v_log_f32 = log2
__device__ __forceinline__ float fast_exp2(float x) { return __builtin_amdgcn_exp2f(x); }  // v_exp_f32 = 2^x
__device__ __forceinline__ float fast_rsq(float x)  { return __builtin_amdgcn_rsqf(x); }

// Branchless inv_sigmoid, valid for q in [0,1) (this input's range).
__device__ __forceinline__ float inv_sigmoid(float q, const KC k) {
    float ssq = fmaf(k.tsig1, q, k.msig1);
    float ratio = (1.f + ssq) * fast_rcp(1.f - ssq);
    return fmaf(fast_log2(ratio), k.atanh_scale, 0.5f);
}

// Branchless ext_sigmoid (q = mitchell sum CAN leave [0,1]; keep selects).
__device__ __forceinline__ float ext_sigmoid(float q, const KC k) {
    float lo = k.slope * q;
    float e  = fast_exp2(fmaf(k.exp_a, q, k.exp_b));
    float th = fmaf(-2.f, fast_rcp(e + 1.f), 1.f);
    float mid = fmaf(k.half_over_sig1, th, 0.5f);
    float v = (q <= 0.f) ? lo : mid;
    return (q >= 1.f) ? (lo + k.one_m_slope) : v;
}

// Branchless Mitchell (exact 0 for |x|>=2 -> natural tap masking)
__device__ __forceinline__ float mitchell_b(float xv) {
    float ax = fabsf(xv);
    float v1 = fmaf(ax * ax, fmaf(7.f / 6.f, ax, -2.f), 8.f / 9.f);
    float v2 = fmaf(fmaf(fmaf(-7.f / 18.f, ax, 2.f), ax, -10.f / 3.f), ax, 16.f / 9.f);
    float v = (ax < 1.f) ? v1 : v2;
    return (ax < 2.f) ? v : 0.f;
}

// Branchless Robidoux
__device__ __forceinline__ float robidoux_b(float r2, const KC k) {
    float r = sqrtf(r2 + 1e-8f);
    float w_in = fmaf(r2, fmaf(-3.f, r, k.a2), k.a0);
    float t = r - 2.f;
    float w_out = (r + k.m_in_root) * (t * t);
    float w = (r2 < 1.f) ? w_in : w_out;
    return (r2 < 4.f) ? w : 0.f;
}

__global__ __launch_bounds__(256, 3)
void lohalo_fused(const float* __restrict__ img, const float* __restrict__ grid,
                  float* __restrict__ out, KC k) {
    __shared__ float sm[SROWS * RS];   // 22400 B
    __shared__ int sred[16];

    // XCD-aware swizzle: 2304 blocks, 288 contiguous per XCD
    const int bid = blockIdx.x;
    const int swz = (bid & 7) * 288 + (bid >> 3);
    const int bx = swz % 48, by = swz / 48;

    const int tid = threadIdx.x;
    const int lx = tid & 15, ly = tid >> 4;
    const int x = bx * 16 + lx;
    const int y = by * 16 + ly;
    const int pix = y * W_OUT + x;

    // ---- Jacobian ----
    const float2* G = (const float2*)grid;
    float2 gc  = G[pix];
    float2 gxm = G[y * W_OUT + max(x - 1, 0)];
    float2 gxp = G[y * W_OUT + min(x + 1, W_OUT - 1)];
    float2 gym = G[max(y - 1, 0) * W_OUT + x];
    float2 gyp = G[min(y + 1, H_OUT - 1) * W_OUT + x];
    float J00 = (gxp.x - gxm.x) * 0.5f, J10 = (gxp.y - gxm.y) * 0.5f;
    float J01 = (gyp.x - gym.x) * 0.5f, J11 = (gyp.y - gym.y) * 0.5f;
    float det = J00 * J11 - J01 * J10 + 1e-8f;
    float idet = fast_rcp(det);
    float a  = J11 * idet, b = -J01 * idet;
    float cI = -J10 * idet, d = J00 * idet;
    float n11 = a * a + b * b, n12 = a * cI + b * d, n22 = cI * cI + d * d;
    float frob = n11 + n22;
    float disc = frob * frob - 4.f * idet * idet;
    float sdisc = sqrtf(fmaxf(disc, 0.f));
    float twice = frob + sdisc;
    float s1s1 = 0.5f * twice, s2s2 = 0.5f * (frob - sdisc);
    float rmaj = fast_rsq(fmaxf(s1s1, 1.f));
    float rmin = fast_rsq(fmaxf(s2s2, 1.f));
    float diff1 = s1s1 - n11, diff2 = s1s1 - n22;
    bool  cnd  = diff1 * diff1 >= diff2 * diff2;
    float tu11 = cnd ? n12 : diff2;
    float tu21 = cnd ? diff1 : n12;
    float nrm = sqrtf(tu11 * tu11 + tu21 * tu21);
    float inrm = fast_rcp(nrm);
    float u11 = nrm > 0.f ? tu11 * inrm : 1.f;
    float u21 = nrm > 0.f ? tu21 * inrm : 0.f;
    float cMx = u11 * rmaj, cMy = u21 * rmaj;
    float cmx = -u21 * rmin, cmy = u11 * rmin;
    float theta = rmaj * rmin;
    bool need_ewa = twice > 2.f;

    float fix = floorf(gc.x), fiy = floorf(gc.y);
    int ix = (int)fix, iy = (int)fiy;
    float fx = gc.x - (fix + 0.5f);
    float fy = gc.y - (fiy + 0.5f);

    // ---- block bbox ----
    int mnx = ix, mxx = ix, mny = iy, mxy = iy;
#pragma unroll
    for (int m = 1; m < 64; m <<= 1) {
        mnx = min(mnx, __shfl_xor(mnx, m));
        mxx = max(mxx, __shfl_xor(mxx, m));
        mny = min(mny, __shfl_xor(mny, m));
        mxy = max(mxy, __shfl_xor(mxy, m));
    }
    const int wid = tid >> 6;
    if ((tid & 63) == 0) {
        sred[wid * 4 + 0] = mnx;
        sred[wid * 4 + 1] = mxx;
        sred[wid * 4 + 2] = mny;
        sred[wid * 4 + 3] = mxy;
    }
    __syncthreads();
    mnx = min(min(sred[0], sred[4]),  min(sred[8],  sred[12]));
    mxx = max(max(sred[1], sred[5]),  max(sred[9],  sred[13]));
    mny = min(min(sred[2], sred[6]),  min(sred[10], sred[14]));
    mxy = max(max(sred[3], sred[7]),  max(sred[11], sred[15]));

    const int x0 = (mnx - 2) & ~3;   // float4-aligned img origin
    const int y0 = mny - 2;
    const bool fits = (mxx + 3 - x0 < SPX) && (mxy + 3 - y0 < SROWS);

    // ---- Mitchell x-weights (mx6[5] is naturally exact 0) ----
    float mx6[6];
#pragma unroll
    for (int t = 0; t < 6; t++) mx6[t] = mitchell_b(fx - (float)(t - 2));
    const float fxp2 = fx + 2.f;

    // packed accumulators: .x = EWA(p), .y = Mitchell(s)
    v2f a0 = {0.f, 0.f}, a1 = {0.f, 0.f}, a2acc = {0.f, 0.f};
    float tw = 0.f;
    const bool any_ewa = __any(need_ewa);

    if (fits) {
        // ---- fused staging: load img, compute sigmoid, write (p,s) pairs ----
        if (x0 >= 0 && x0 + SPX <= W_IN) {
            for (int j = tid; j < NLD4; j += 256) {
                int p   = j / (SROWS * (SPX / 4));
                int rem = j - p * (SROWS * (SPX / 4));
                int r   = rem >> 3;
                int q   = rem & 7;
                int gr  = min(max(y0 + r, 0), H_IN - 1);
                float4 v = *(const float4*)&img[(size_t)p * HW_IN + (size_t)gr * W_IN + x0 + q * 4];
                float* o = &sm[r * RS + (q * 4) * 6 + p * 2];
                *(float2*)(o)      = make_float2(v.x, inv_sigmoid(v.x, k));
                *(float2*)(o + 6)  = make_float2(v.y, inv_sigmoid(v.y, k));
                *(float2*)(o + 12) = make_float2(v.z, inv_sigmoid(v.z, k));
                *(float2*)(o + 18) = make_float2(v.w, inv_sigmoid(v.w, k));
            }
        } else {
            for (int j = tid; j < SROWS * SPX; j += 256) {
                int r = j / SPX;
                int c = j - r * SPX;
                int gr  = min(max(y0 + r, 0), H_IN - 1);
                int gcc = min(max(x0 + c, 0), W_IN - 1);
                const float* base = &img[(size_t)gr * W_IN + gcc];
                int o = r * RS + c * 6;
#pragma unroll
                for (int p = 0; p < 3; p++) {
                    float pv = base[(size_t)p * HW_IN];
                    *(float2*)&sm[o + p * 2] = make_float2(pv, inv_sigmoid(pv, k));
                }
            }
        }
        __syncthreads();

        const float* sp = &sm[(iy - 2 - y0) * RS + (ix - 2 - x0) * 6];
        if (any_ewa) {
            const v2f cM = {cMx, cmx};
#pragma unroll
            for (int ty = 0; ty < 6; ty++) {
                float rely = fy - (float)(ty - 2);
                float wmy = mitchell_b(rely);          // exact 0 for ty=5 band
                v2f q = { fmaf(fxp2, cMx, rely * cMy),
                          fmaf(fxp2, cmx, rely * cmy) };
                float mxw[6];
#pragma unroll
                for (int t = 0; t < 6; t++) mxw[t] = mx6[t] * wmy;
                const float* rp = sp + ty * RS;
#pragma unroll
                for (int tx = 0; tx < 6; tx++) {
                    v2f f0 = *(const v2f*)(rp + tx * 6);
                    v2f f1 = *(const v2f*)(rp + tx * 6 + 2);
                    v2f f2 = *(const v2f*)(rp + tx * 6 + 4);
                    float r2 = fmaf(q.x, q.x, q.y * q.y);
                    float we = robidoux_b(r2, k);
                    tw += we;
                    v2f w = { we, mxw[tx] };
                    a0    = __builtin_elementwise_fma(f0, w, a0);
                    a1    = __builtin_elementwise_fma(f1, w, a1);
                    a2acc = __builtin_elementwise_fma(f2, w, a2acc);
                    q = q - cM;
                }
            }
        } else {
#pragma unroll
            for (int ty = 0; ty < 5; ty++) {
                float rely = fy - (float)(ty - 2);
                float wmy = mitchell_b(rely);
                const float* rp = sp + ty * RS;
                float rs0 = 0.f, rs1 = 0.f, rs2 = 0.f;
#pragma unroll
                for (int tx = 0; tx < 5; tx++) {
                    float mxv = mx6[tx];
                    rs0 = fmaf((rp + tx * 6)[1], mxv, rs0);
                    rs1 = fmaf((rp + tx * 6)[3], mxv, rs1);
                    rs2 = fmaf((rp + tx * 6)[5], mxv, rs2);
                }
                a0.y    = fmaf(rs0, wmy, a0.y);
                a1.y    = fmaf(rs1, wmy, a1.y);
                a2acc.y = fmaf(rs2, wmy, a2acc.y);
            }
        }
    } else {
        // safety net: direct gather from img with per-tap clamp + sigmoid
#pragma unroll
        for (int ty = 0; ty < 6; ty++) {
            float rely = fy - (float)(ty - 2);
            float wmy = mitchell_b(rely);
            float q1 = fmaf(fxp2, cMx, rely * cMy);
            float q2 = fmaf(fxp2, cmx, rely * cmy);
            const int gy2 = min(max(iy + (ty - 2), 0), H_IN - 1);
            const int rb = gy2 * W_IN;
#pragma unroll
            for (int tx = 0; tx < 6; tx++) {
                const int off = rb + min(max(ix + (tx - 2), 0), W_IN - 1);
                float p0 = img[off];
                float p1 = img[off + HW_IN];
                float p2 = img[off + 2 * HW_IN];
                float mxw = mx6[tx] * wmy;
                float r2 = fmaf(q1, q1, q2 * q2);
                float we = robidoux_b(r2, k);
                tw += we;
                a0.x    = fmaf(p0, we, a0.x);
                a1.x    = fmaf(p1, we, a1.x);
                a2acc.x = fmaf(p2, we, a2acc.x);
                a0.y    = fmaf(inv_sigmoid(p0, k), mxw, a0.y);
                a1.y    = fmaf(inv_sigmoid(p1, k), mxw, a1.y);
                a2acc.y = fmaf(inv_sigmoid(p2, k), mxw, a2acc.y);
                q1 -= cMx;
                q2 -= cmx;
            }
        }
    }

    tw += 1e-8f;
    float itw = fast_rcp(tw);
    float mv0 = ext_sigmoid(a0.y, k);
    float mv1 = ext_sigmoid(a1.y, k);
    float mv2 = ext_sigmoid(a2acc.y, k);
    float om = 1.f - theta;
    out[pix]              = need_ewa ? theta * mv0 + om * (a0.x * itw)    : mv0;
    out[HW_OUT + pix]     = need_ewa ? theta * mv1 + om * (a1.x * itw)    : mv1;
    out[2 * HW_OUT + pix] = need_ewa ? theta * mv2 + om * (a2acc.x * itw) : mv2;
}

extern "C" void kernel_launch(void* const* d_in, const int* in_sizes, int n_in,
                              void* d_out, int out_size, void* d_ws, size_t ws_size,
                              hipStream_t stream) {
    const float* img  = (const float*)d_in[0];
    const float* grid = (const float*)d_in[1];
    float* out = (float*)d_out;

    KC k;
    const double cc = 3.38589;
    const double s1 = tanh(0.25 * cc);
    const double slope = (1.0 / s1 - s1) * 0.25 * cc;
    const double log2e = 1.4426950408889634074;
    const double ln2   = 0.6931471805599453094;
    k.tsig1 = (float)(2.0 * s1);
    k.msig1 = (float)(-s1);
    k.atanh_scale = (float)(ln2 / cc);            // (2/c)*atanh = (ln2/c)*log2
    k.slope = (float)slope;
    k.one_m_slope = (float)(1.0 - slope);
    k.half_over_sig1 = (float)(0.5 / s1);
    k.exp_a = (float)(cc * log2e);
    k.exp_b = (float)(-0.5 * cc * log2e);
    const double sq2 = sqrt(2.0);
    k.a2 = (float)((45739.0 + 7164.0 * sq2) / 10319.0);
    k.a0 = (float)((-8926.0 - 14328.0 * sq2) / 10319.0);
    k.m_in_root = (float)((-103.0 - 36.0 * sq2) / (7.0 + 72.0 * sq2));

    lohalo_fused<<<(W_OUT / 16) * (H_OUT / 16), 256, 0, stream>>>(img, grid, out, k);
}